// Round 7
// baseline (335.711 us; speedup 1.0000x reference)
//
#include <hip/hip_runtime.h>
#include <hip/hip_bf16.h>
#include <math.h>

#define BB 16
#define TT 512
#define NN 128
#define PREDN 256
#define DMC 32
#define LL 768
constexpr float EPSF = 1e-5f;
using bf16 = __hip_bfloat16;
using frag_ab = __attribute__((ext_vector_type(8))) short;   // 8 bf16
using frag_cd = __attribute__((ext_vector_type(4))) float;   // 4 f32

__device__ __forceinline__ unsigned pbf2(float a, float b){
  union { bf16 h; unsigned short u; } x, y;
  x.h = __float2bfloat16(a); y.h = __float2bfloat16(b);
  return (unsigned)x.u | ((unsigned)y.u << 16);
}

__device__ __forceinline__ unsigned short bf16b(float v){
  union { bf16 h; unsigned short u; } x;
  x.h = __float2bfloat16(v);
  return x.u;
}

__device__ __forceinline__ float gelu_fast(float s){
  float s2v = s*s;
  float e = exp2f(s*fmaf(s2v, 0.10294396f, 2.30211806f));
  return s*e*__builtin_amdgcn_rcpf(e + 1.f);
}

// ---------------- K_pre: norm front-end (stats+mu/sd+xbf) + weight transposes + bf16 packing ----------------
// Roles by blockIdx.x:
//   [0,128)    norm: block=(b, 16-col group): stats + muv/sdv + xbf
//   [128,256)  wT1 transpose
//   [256,384)  wT2 transpose
//   384        bwpk/awpk/bsum packing
//   [385,513)  lewbf packing
//   [513,577)  ldwbf packing
__global__ void k_pre(const float* __restrict__ bx, const float* __restrict__ v0,
                      const float* __restrict__ v1, const float* __restrict__ w1c,
                      const float* __restrict__ w2c, const float* __restrict__ w0s1,
                      const float* __restrict__ w1s1, const float* __restrict__ b0s1,
                      const float* __restrict__ b1s1, const float* __restrict__ lew,
                      const float* __restrict__ ldw,
                      float* __restrict__ muv, float* __restrict__ sdv,
                      unsigned short* __restrict__ xbf,
                      float* __restrict__ wT1, float* __restrict__ wT2,
                      uint4* __restrict__ bwpk, uint4* __restrict__ awpk,
                      float* __restrict__ bsum, unsigned* __restrict__ lewbf,
                      unsigned* __restrict__ ldwbf){
  __shared__ float sr[8][16], s2r[8][16], bmu[16], brs[16];
  int blk = blockIdx.x;
  int tid = threadIdx.x;
  if(blk < 128){
    int b = blk >> 3, n0 = (blk & 7)*16;
    int c = tid & 15, ch = tid >> 4;        // 8 chunks of 64 t
    const float* p = bx + ((size_t)b*TT + ch*64)*NN + n0 + c;
    float s = 0.f, s2 = 0.f;
    for(int t=0;t<64;t++){ float v = p[(size_t)t*NN]; s += v; s2 += v*v; }
    sr[ch][c] = s; s2r[ch][c] = s2;
    __syncthreads();
    if(tid < 16){
      float ss = 0.f, ss2 = 0.f;
      #pragma unroll
      for(int k2=0;k2<8;k2++){ ss += sr[k2][tid]; ss2 += s2r[k2][tid]; }
      float m = ss*(1.f/512.f);
      float var = fmaxf(ss2*(1.f/512.f) - m*m, 0.f);
      float sd = sqrtf(var + EPSF);
      muv[b*NN + n0 + tid] = m;
      sdv[b*NN + n0 + tid] = sd;
      bmu[tid] = m; brs[tid] = 1.f/sd;
    }
    __syncthreads();
    for(int i=tid; i<512*8; i+=128){
      int t = i >> 3, cp = i & 7;
      const float* q = bx + ((size_t)b*TT + t)*NN + n0 + cp*2;
      float v0x = (q[0] - bmu[cp*2])*brs[cp*2];
      float v1x = (q[1] - bmu[cp*2+1])*brs[cp*2+1];
      *(unsigned*)&xbf[((size_t)b*TT + t)*NN + n0 + cp*2] = pbf2(v0x, v1x);
    }
  } else if(blk < 256){
    int o = blk - 128;
    for(int k=tid; k<1536; k+=128)
      wT1[(size_t)k*NN + o] = w1c[(size_t)o*1536 + k];
  } else if(blk < 384){
    int o = blk - 256;
    for(int k=tid; k<512; k+=128)
      wT2[(size_t)k*NN + o] = w2c[(size_t)o*512 + k];
  } else if(blk == 384){
    int i = tid;
    {
      int c = i >> 2, kq = i & 3;
      float w8[8];
      #pragma unroll
      for(int j=0;j<8;j++){
        int k = kq*8+j; float w = 0.f;
        if(k < 27){
          int ci = k/9, r9 = k - ci*9, dy = r9/3, dx = r9 - dy*3;
          w = 0.5f*w1s1[((c*3+ci)*3+dy)*3+dx];
          if(dy==1 && dx==1) w += 0.5f*w0s1[c*3+ci];
        }
        w8[j] = w;
      }
      bwpk[i] = make_uint4(pbf2(w8[0],w8[1]), pbf2(w8[2],w8[3]),
                           pbf2(w8[4],w8[5]), pbf2(w8[6],w8[7]));
    }
    if(i < 36){
      int tap = i >> 2, qq = i & 3, c8 = qq*8;
      float w8[8];
      #pragma unroll
      for(int j=0;j<8;j++){
        int c = c8 + j;
        w8[j] = 0.5f*v1[c*9 + tap] + ((tap==4) ? 0.5f*v0[c] : 0.f);
      }
      awpk[i] = make_uint4(pbf2(w8[0],w8[1]), pbf2(w8[2],w8[3]),
                           pbf2(w8[4],w8[5]), pbf2(w8[6],w8[7]));
    }
    if(i < 32) bsum[i] = 0.5f*(b0s1[i] + b1s1[i]);
  } else if(blk < 513){
    int o = blk - 385;              // rows l = o*6..o*6+5
    for(int i=tid; i<1536; i+=128){
      int l = o*6 + i/256, tp = i%256;
      lewbf[(size_t)l*256 + tp] = pbf2(lew[(size_t)l*TT + 2*tp], lew[(size_t)l*TT + 2*tp + 1]);
    }
  } else {
    int o = blk - 513;              // rows p = o*4..o*4+3
    for(int i=tid; i<1536; i+=128){
      int p = o*4 + i/384, tp = i%384;
      ldwbf[(size_t)p*384 + tp] = pbf2(ldw[(size_t)p*LL + 2*tp], ldw[(size_t)p*LL + 2*tp + 1]);
    }
  }
}

// ---------------- K1: GEMM1 via bf16 MFMA, A/B from pre-packed bf16 ----------------
__global__ __launch_bounds__(256) void k_gemm1(const unsigned short* __restrict__ xbf,
    const unsigned* __restrict__ lewbf, const float* __restrict__ leb,
    float* __restrict__ x, float* __restrict__ a0){
  __shared__ unsigned Asu[64*20];
  __shared__ unsigned Bsu[64*20];
  int tid = threadIdx.x;
  int row0 = blockIdx.x*64, l0 = blockIdx.y*64;
  int b = row0 >> 7, n0 = row0 & 127;
  int lane = tid & 63, wv = tid >> 6;
  frag_cd acc[4] = {};
  int an = tid & 63, akq = (tid >> 6)*8;
  int btk = tid & 15, blc = tid >> 4;
  unsigned ra[4], rbq[4];
  #pragma unroll
  for(int u=0;u<4;u++){
    unsigned lo = xbf[((size_t)b*TT + akq + 2*u)*NN + n0 + an];
    unsigned hi = xbf[((size_t)b*TT + akq + 2*u + 1)*NN + n0 + an];
    ra[u] = lo | (hi << 16);
    rbq[u] = lewbf[(size_t)(l0 + blc + 16*u)*256 + btk];
  }
  int fr = wv*16 + (lane & 15);
  int fq = (lane >> 4)*4;
  for(int k0=0;k0<TT;k0+=32){
    *(uint4*)&Asu[an*20 + (akq>>1)] = make_uint4(ra[0], ra[1], ra[2], ra[3]);
    #pragma unroll
    for(int p=0;p<4;p++) Bsu[(blc + 16*p)*20 + btk] = rbq[p];
    __syncthreads();
    if(k0 + 32 < TT){
      #pragma unroll
      for(int u=0;u<4;u++){
        unsigned lo = xbf[((size_t)b*TT + k0 + 32 + akq + 2*u)*NN + n0 + an];
        unsigned hi = xbf[((size_t)b*TT + k0 + 32 + akq + 2*u + 1)*NN + n0 + an];
        ra[u] = lo | (hi << 16);
        rbq[u] = lewbf[(size_t)(l0 + blc + 16*u)*256 + ((k0 + 32) >> 1) + btk];
      }
    }
    frag_ab af = *(const frag_ab*)&Asu[fr*20 + fq];
    #pragma unroll
    for(int nt=0;nt<4;nt++){
      frag_ab bf = *(const frag_ab*)&Bsu[(nt*16 + (lane & 15))*20 + fq];
      acc[nt] = __builtin_amdgcn_mfma_f32_16x16x32_bf16(af, bf, acc[nt], 0, 0, 0);
    }
    __syncthreads();
  }
  int col = lane & 15, quad = lane >> 4;
  #pragma unroll
  for(int nt=0;nt<4;nt++){
    int l = l0 + nt*16 + col;
    float lb = leb[l];
    #pragma unroll
    for(int r=0;r<4;r++){
      int m = wv*16 + quad*4 + r;
      x[(size_t)(row0 + m)*LL + l] = acc[nt][r] + lb;
    }
    float4 st;
    st.x = acc[nt][0] + lb;
    st.y = acc[nt][1] + lb;
    st.z = acc[nt][2] + lb;
    st.w = acc[nt][3] + lb;
    *(float4*)&a0[((size_t)b*LL + l)*NN + n0 + wv*16 + quad*4] = st;
  }
}

// ---------------- K3: conv1 (coalesced wT, 4 j per block) ----------------
__global__ __launch_bounds__(512) void k_conv1(const float* __restrict__ x, const float* __restrict__ wT,
                                               const float* __restrict__ bias, float* __restrict__ t1){
  __shared__ alignas(16) float xs[NN*48];
  int jt = blockIdx.x, b = blockIdx.y;
  int tid = threadIdx.x;
  int o = tid & 127, jj = tid >> 7;
  for(int i=tid;i<NN*48;i+=512){
    int ci = i/48, kk = i%48;
    xs[i] = x[((size_t)b*NN + ci)*LL + jt*48 + kk];
  }
  __syncthreads();
  float a0 = 0.f, a1 = 0.f, a2 = 0.f, a3 = 0.f;
  for(int ci=0;ci<NN;ci++){
    const float* xc = xs + ci*48 + jj*12;
    const float* wc = wT + (size_t)(ci*12)*NN + o;
    #pragma unroll
    for(int kk=0;kk<12;kk+=4){
      a0 = fmaf(xc[kk+0], wc[(size_t)(kk+0)*NN], a0);
      a1 = fmaf(xc[kk+1], wc[(size_t)(kk+1)*NN], a1);
      a2 = fmaf(xc[kk+2], wc[(size_t)(kk+2)*NN], a2);
      a3 = fmaf(xc[kk+3], wc[(size_t)(kk+3)*NN], a3);
    }
  }
  int j = jt*4 + jj;
  t1[((size_t)b*NN + o)*64 + j] = (a0 + a1) + (a2 + a3) + bias[o];
}

// ---------------- K_bs64: BN stats + BN/ELU/transpose + spline Thomas + conv2, all per-b block ----------------
__global__ __launch_bounds__(256) void k_bs64(const float* __restrict__ t1, const float* __restrict__ g,
    const float* __restrict__ bb, const float* __restrict__ wT2, const float* __restrict__ c2b,
    float* __restrict__ t1t, float* __restrict__ M, float* __restrict__ t2){
  __shared__ float yt[64][NN+1];
  __shared__ float cp[62];
  __shared__ float dp[62][NN];
  __shared__ float sc[NN], sh[NN];
  int b = blockIdx.x, tid = threadIdx.x;
  int w = tid >> 6, jl = tid & 63;
  // phase 0: channel stats over all b (deterministic: fixed chunking + butterfly)
  for(int og=0; og<32; og++){
    int o = og*4 + w;
    float s = 0.f, s2 = 0.f;
    const float* p = t1 + (size_t)o*64 + jl;
    #pragma unroll 4
    for(int bp=0; bp<16; bp++){ float v = p[(size_t)bp*8192]; s += v; s2 += v*v; }
    #pragma unroll
    for(int m2=1; m2<64; m2<<=1){ s += __shfl_xor(s, m2, 64); s2 += __shfl_xor(s2, m2, 64); }
    if(jl == 0){
      float mu = s/1024.f;
      float var = fmaxf(s2/1024.f - mu*mu, 0.f);
      float scv = g[o]*rsqrtf(var + EPSF);
      sc[o] = scv; sh[o] = bb[o] - mu*scv;
    }
  }
  if(tid == 0){
    float cv = 0.25f; cp[0] = cv;
    for(int i=1;i<62;i++){ cv = 1.f/(4.f - cv); cp[i] = cv; }
  }
  __syncthreads();
  // phase 1: BN+ELU own b -> yt
  const float* tb = t1 + (size_t)b*8192;
  for(int i=tid; i<8192; i+=256){
    int o = i >> 6;
    float v = tb[i]*sc[o] + sh[o];
    v = v > 0.f ? v : (expf(v) - 1.f);
    yt[i & 63][o] = v;
  }
  __syncthreads();
  // phase 1b: coalesced t1t writeback [b][j][o]
  for(int i=tid; i<8192; i+=256){
    int j = i >> 7, o = i & 127;
    t1t[((size_t)b*64 + j)*NN + o] = yt[j][o];
  }
  // phase 2: Thomas solve per channel (waves 0-1); waves 2-3 skip straight to conv2
  if(tid < NN){
    int c = tid;
    const float Kc = 6.f*63.f*63.f;
    float y0 = yt[0][c], y1 = yt[1][c];
    float dprev = 0.f;
    for(int i=0;i<62;i++){
      float y2 = yt[i+2][c];
      float r = (y2 - 2.f*y1 + y0)*Kc;
      float d = (i == 0) ? r*0.25f : (r - dprev)*cp[i];
      dp[i][c] = d; dprev = d;
      y0 = y1; y1 = y2;
    }
    float* Mb = M + (size_t)b*64*NN + c;
    float xv = dp[61][c];
    Mb[(size_t)62*NN] = xv;
    for(int i=60;i>=0;i--){
      xv = dp[i][c] - cp[i]*xv;
      Mb[(size_t)(i+1)*NN] = xv;
    }
    Mb[0] = 0.f;
    Mb[(size_t)63*NN] = 0.f;
  }
  // phase 3: conv2 from yt (LDS broadcast), 128 o x 2 j-halves
  {
    int o = tid & 127, jh = tid >> 7;
    float acc[8] = {};
    for(int ci=0; ci<NN; ci++){
      const float* wc = wT2 + (size_t)(ci*4)*NN + o;
      float w0 = wc[0], w1 = wc[NN], w2 = wc[2*NN], w3 = wc[3*NN];
      #pragma unroll
      for(int jj=0;jj<8;jj++){
        int r = (jh*8 + jj)*4;
        acc[jj] = fmaf(yt[r][ci],   w0, acc[jj]);
        acc[jj] = fmaf(yt[r+1][ci], w1, acc[jj]);
        acc[jj] = fmaf(yt[r+2][ci], w2, acc[jj]);
        acc[jj] = fmaf(yt[r+3][ci], w3, acc[jj]);
      }
    }
    float bias = c2b[o];
    #pragma unroll
    for(int jj=0;jj<8;jj++)
      t2[((size_t)b*NN + o)*16 + jh*8 + jj] = acc[jj] + bias;
  }
}

// ---------------- K_bs16: BN stats + BN/ELU/transpose + spline Thomas (LK=16) ----------------
__global__ __launch_bounds__(256) void k_bs16(const float* __restrict__ t2, const float* __restrict__ g,
    const float* __restrict__ bb, float* __restrict__ t2t, float* __restrict__ M){
  __shared__ float yt[16][NN+1];
  __shared__ float cp[14];
  __shared__ float dp[14][NN];
  __shared__ float sc[NN], sh[NN];
  int b = blockIdx.x, tid = threadIdx.x;
  int w = tid >> 6, lane = tid & 63;
  int j = lane & 15, b4 = lane >> 4;
  for(int og=0; og<32; og++){
    int o = og*4 + w;
    float s = 0.f, s2 = 0.f;
    #pragma unroll
    for(int q=0;q<4;q++){
      float v = t2[(((size_t)(b4*4+q))*NN + o)*16 + j];
      s += v; s2 += v*v;
    }
    #pragma unroll
    for(int m2=1; m2<64; m2<<=1){ s += __shfl_xor(s, m2, 64); s2 += __shfl_xor(s2, m2, 64); }
    if(lane == 0){
      float mu = s/256.f;
      float var = fmaxf(s2/256.f - mu*mu, 0.f);
      float scv = g[o]*rsqrtf(var + EPSF);
      sc[o] = scv; sh[o] = bb[o] - mu*scv;
    }
  }
  if(tid == 0){
    float cv = 0.25f; cp[0] = cv;
    for(int i=1;i<14;i++){ cv = 1.f/(4.f - cv); cp[i] = cv; }
  }
  __syncthreads();
  const float* tb = t2 + (size_t)b*2048;
  for(int i=tid; i<2048; i+=256){
    int o = i >> 4;
    float v = tb[i]*sc[o] + sh[o];
    v = v > 0.f ? v : (expf(v) - 1.f);
    yt[i & 15][o] = v;
  }
  __syncthreads();
  for(int i=tid; i<2048; i+=256){
    int jj = i >> 7, o = i & 127;
    t2t[((size_t)b*16 + jj)*NN + o] = yt[jj][o];
  }
  if(tid < NN){
    int c = tid;
    const float Kc = 6.f*15.f*15.f;
    float y0 = yt[0][c], y1 = yt[1][c];
    float dprev = 0.f;
    for(int i=0;i<14;i++){
      float y2 = yt[i+2][c];
      float r = (y2 - 2.f*y1 + y0)*Kc;
      float d = (i == 0) ? r*0.25f : (r - dprev)*cp[i];
      dp[i][c] = d; dprev = d;
      y0 = y1; y1 = y2;
    }
    float* Mb = M + (size_t)b*16*NN + c;
    float xv = dp[13][c];
    Mb[(size_t)14*NN] = xv;
    for(int i=12;i>=0;i--){
      xv = dp[i][c] - cp[i]*xv;
      Mb[(size_t)(i+1)*NN] = xv;
    }
    Mb[0] = 0.f;
    Mb[(size_t)15*NN] = 0.f;
  }
}

// ---------------- spline pair evaluation (compile-time LK; shared coefficients for 2 adjacent channels) ----------------
template<int LK>
__device__ __forceinline__ void spline_pair(const float* __restrict__ y, const float* __restrict__ M,
    int l, int b, int c0, bool ok0, bool ok1, float& v0, float& v1){
  const float hh = 1.f/(LK-1);
  float q = (float)l * (1.f/(LL-1));
  int idx = (int)floorf(q*(LK-1));
  if(idx > LK-2) idx = LK-2;
  float s = q - idx*hh;
  float u = hh - s;
  const float hh6 = hh*hh/6.f;
  const float i6h = 1.f/(6.f*hh);
  const float ih = 1.f/hh;
  float cu = u*u*u, cs = s*s*s;
  float uh = u*ih, sh = s*ih;
  const float* yb = y + ((size_t)b*LK + idx)*NN + c0;
  const float* Mb = M + ((size_t)b*LK + idx)*NN + c0;
  v0 = 0.f; v1 = 0.f;
  if(ok0){
    float yi = yb[0], yi1 = yb[NN], M0 = Mb[0], M1 = Mb[NN];
    v0 = (M0*cu + M1*cs)*i6h + (yi - M0*hh6)*uh + (yi1 - M1*hh6)*sh;
  }
  if(ok1){
    float yi = yb[1], yi1 = yb[NN+1], M0 = Mb[1], M1 = Mb[NN+1];
    v1 = (M0*cu + M1*cs)*i6h + (yi - M0*hh6)*uh + (yi1 - M1*hh6)*sh;
  }
}

// tap offset table for im2col: k = ci*9 + dy*3 + dx -> ushort offset into AsBf[3][12][36]
constexpr int KOFF[27] = {
    0,   1,   2,  36,  37,  38,  72,  73,  74,
  432, 433, 434, 468, 469, 470, 504, 505, 506,
  864, 865, 866, 900, 901, 902, 936, 937, 938
};

// ---------------- K_h12: fully-MFMA fused stage-1 conv + GELU + stage-2 conv + residual ----------------
#define PBQ 1416
__global__ __launch_bounds__(256, 5) void k_h12(const float* __restrict__ a0,
    const float* __restrict__ y64, const float* __restrict__ M64,
    const float* __restrict__ y16, const float* __restrict__ M16,
    const uint4* __restrict__ bwpk, const uint4* __restrict__ awpk,
    const float* __restrict__ bsum, const float* __restrict__ vb0,
    const float* __restrict__ vb1, unsigned short* __restrict__ cobf){
  __shared__ alignas(16) unsigned short AsBf[3*12*36];   // bf16 a-tile [ch][yy][xx]
  __shared__ alignas(16) unsigned Au[4*PBQ];             // planar patch/h1 buffer
  int tid = threadIdx.x;
  int l0 = blockIdx.x*8, n0 = blockIdx.y*32, b = blockIdx.z;
  int lane = tid & 63, wv = tid >> 6;
  int colB = lane & 15, qg = lane >> 4;

  // ---- Phase A: stage a-tile as bf16 pairs (648 uint slots) ----
  for(int i=tid; i<648; i+=256){
    int ch = i/216, rem = i%216, yy = rem/18, xxp = rem%18;
    int xx = xxp*2;
    int gl = l0 + yy - 2, gn0 = n0 + xx - 2;
    bool okl = (gl >= 0 && gl < LL);
    bool ok0 = okl && ((unsigned)gn0 < (unsigned)NN);
    bool ok1 = okl && ((unsigned)(gn0+1) < (unsigned)NN);
    float v0 = 0.f, v1 = 0.f;
    if(ch == 0){
      if(ok0) v0 = a0[((size_t)b*LL + gl)*NN + gn0];
      if(ok1) v1 = a0[((size_t)b*LL + gl)*NN + gn0 + 1];
    } else if(okl){
      if(ch == 1) spline_pair<64>(y64, M64, gl, b, gn0, ok0, ok1, v0, v1);
      else        spline_pair<16>(y16, M16, gl, b, gn0, ok0, ok1, v0, v1);
    }
    *(unsigned*)&AsBf[i*2] = pbf2(v0, v1);
  }

  // ---- pre-packed stage-1 weight fragments + biases ----
  union U4 { uint4 q; frag_ab f; };
  U4 bw0, bw1;
  bw0.q = bwpk[colB*4 + qg];
  bw1.q = bwpk[(colB + 16)*4 + qg];
  float brA[4], brB[4];
  #pragma unroll
  for(int r=0;r<4;r++){ brA[r] = bsum[qg*4 + r]; brB[r] = bsum[16 + qg*4 + r]; }
  __syncthreads();

  // ---- Phase B1: build patches, 1 thread per 2 adjacent px (aligned u32 pair reads) ----
  {
    const unsigned* Uv = (const unsigned*)AsBf;   // u32 view: [3][12][18]
    if(tid < 176){
      if(tid < 170){
        int yy = tid/17, xp = tid - yy*17;        // px pair (yy, 2xp), (yy, 2xp+1)
        unsigned g[3][3][2];
        #pragma unroll
        for(int ci=0;ci<3;ci++)
          #pragma unroll
          for(int dy=0;dy<3;dy++){
            int base = (ci*12 + yy + dy)*18 + xp;
            g[ci][dy][0] = Uv[base];
            g[ci][dy][1] = Uv[base+1];
          }
        int px0 = yy*34 + 2*xp;
        uint4 pq;
        pq.x = g[0][0][0];
        pq.y = (g[0][0][1]&0xffffu) | (g[0][1][0]<<16);
        pq.z = (g[0][1][0]>>16) | (g[0][1][1]<<16);
        pq.w = g[0][2][0];
        *(uint4*)&Au[0*PBQ + px0*4] = pq;
        pq.x = (g[0][2][1]&0xffffu) | (g[1][0][0]<<16);
        pq.y = (g[1][0][0]>>16) | (g[1][0][1]<<16);
        pq.z = g[1][1][0];
        pq.w = (g[1][1][1]&0xffffu) | (g[1][2][0]<<16);
        *(uint4*)&Au[1*PBQ + px0*4] = pq;
        pq.x = (g[1][2][0]>>16) | (g[1][2][1]<<16);
        pq.y = g[2][0][0];
        pq.z = (g[2][0][1]&0xffffu) | (g[2][1][0]<<16);
        pq.w = (g[2][1][0]>>16) | (g[2][1][1]<<16);
        *(uint4*)&Au[2*PBQ + px0*4] = pq;
        pq.x = g[2][2][0];
        pq.y = g[2][2][1]&0xffffu;
        pq.z = 0u; pq.w = 0u;
        *(uint4*)&Au[3*PBQ + px0*4] = pq;
        int px1 = px0 + 1;
        pq.x = (g[0][0][0]>>16) | (g[0][0][1]<<16);
        pq.y = (g[0][0][1]>>16) | (g[0][1][0]&0xffff0000u);
        pq.z = g[0][1][1];
        pq.w = (g[0][2][0]>>16) | (g[0][2][1]<<16);
        *(uint4*)&Au[0*PBQ + px1*4] = pq;
        pq.x = (g[0][2][1]>>16) | (g[1][0][0]&0xffff0000u);
        pq.y = g[1][0][1];
        pq.z = (g[1][1][0]>>16) | (g[1][1][1]<<16);
        pq.w = (g[1][1][1]>>16) | (g[1][2][0]&0xffff0000u);
        *(uint4*)&Au[1*PBQ + px1*4] = pq;
        pq.x = g[1][2][1];
        pq.y = (g[2][0][0]>>16) | (g[2][0][1]<<16);
        pq.z = (g[2][0][1]>>16) | (g[2][1][0]&0xffff0000u);
        pq.w = g[2][1][1];
        *(uint4*)&Au[2*PBQ + px1*4] = pq;
        pq.x = (g[2][2][0]>>16) | (g[2][2][1]<<16);
        pq.y = g[2][2][1]>>16;
        pq.z = 0u; pq.w = 0u;
        *(uint4*)&Au[3*PBQ + px1*4] = pq;
      } else {
        int px = 340 + (tid-170)*2;
        uint4 z = make_uint4(0u,0u,0u,0u);
        #pragma unroll
        for(int q=0;q<4;q++){
          *(uint4*)&Au[q*PBQ + px*4]     = z;
          *(uint4*)&Au[q*PBQ + (px+1)*4] = z;
        }
      }
    }
  }
  __syncthreads();

  // ---- Phase B2: stage-1 MFMA (A=weights, B=patches), gelu, b64 writeback ----
  unsigned short* h1h = (unsigned short*)Au;
  frag_cd zac = {0.f, 0.f, 0.f, 0.f};
  for(int t = wv; t < 22; t += 4){
    int px = t*16 + colB;
    U4 av;
    av.q = *(const uint4*)&Au[qg*PBQ + px*4];
    frag_cd d0 = __builtin_amdgcn_mfma_f32_16x16x32_bf16(bw0.f, av.f, zac, 0, 0, 0);
    frag_cd d1 = __builtin_amdgcn_mfma_f32_16x16x32_bf16(bw1.f, av.f, zac, 0, 0, 0);
    unsigned u0 = pbf2(gelu_fast(d0[0] + brA[0]), gelu_fast(d0[1] + brA[1]));
    unsigned u1 = pbf2(gelu_fast(d0[2] + brA[2]), gelu_fast(d0[3] + brA[3]));
    unsigned u2 = pbf2(gelu_fast(d1[0] + brB[0]), gelu_fast(d1[1] + brB[1]));
    unsigned u3 = pbf2(gelu_fast(d1[2] + brB[2]), gelu_fast(d1[3] + brB[3]));
    int lo = (qg >> 1)*PBQ + px*4 + (qg & 1)*2;
    *(uint2*)&Au[lo]           = make_uint2(u0, u1);
    *(uint2*)&Au[2*PBQ + lo]   = make_uint2(u2, u3);
  }
  __syncthreads();

  // ---- Phase B3: zero h1 at invalid borders ----
  if(n0 == 0){
    for(int i=tid;i<10*32;i+=256){ int yy=i>>5, ch=i&31;
      h1h[((ch>>3)*PBQ + (yy*34)*4)*2 + (ch&7)] = 0; }
  }
  if(n0 == 96){
    for(int i=tid;i<10*32;i+=256){ int yy=i>>5, ch=i&31;
      h1h[((ch>>3)*PBQ + (yy*34+33)*4)*2 + (ch&7)] = 0; }
  }
  if(l0 == 0){
    for(int i=tid;i<34*32;i+=256){ int xx=i>>5, ch=i&31;
      h1h[((ch>>3)*PBQ + xx*4)*2 + (ch&7)] = 0; }
  }
  if(l0 == 760){
    for(int i=tid;i<34*32;i+=256){ int xx=i>>5, ch=i&31;
      h1h[((ch>>3)*PBQ + (9*34+xx)*4)*2 + (ch&7)] = 0; }
  }

  // ---- pre-packed stage-2 weight fragments ----
  U4 aw[9];
  #pragma unroll
  for(int tap=0; tap<9; tap++) aw[tap].q = awpk[tap*4 + qg];
  float vbsum = vb0[0] + vb1[0];
  __syncthreads();

  // ---- Phase C: stage-2 conv via MFMA, B-frags direct from planar h1 ----
  frag_cd cacc[4] = {};
  int baseoff[4];
  #pragma unroll
  for(int tt=0; tt<4; tt++){
    int px = (wv*4 + tt)*16 + colB;
    int yy = px >> 5, xx = px & 31;
    baseoff[tt] = qg*PBQ + (yy*34 + xx)*4;
  }
  #pragma unroll
  for(int dy=0; dy<3; dy++)
    #pragma unroll
    for(int dx=0; dx<3; dx++){
      int tap = dy*3 + dx;
      int off = (dy*34 + dx)*4;
      #pragma unroll
      for(int tt=0; tt<4; tt++){
        U4 bv;
        bv.q = *(const uint4*)&Au[baseoff[tt] + off];
        cacc[tt] = __builtin_amdgcn_mfma_f32_16x16x32_bf16(aw[tap].f, bv.f, cacc[tt], 0, 0, 0);
      }
    }
  if(lane < 16){
    #pragma unroll
    for(int tt=0; tt<4; tt++){
      int px = (wv*4 + tt)*16 + lane;
      int yy = px >> 5, xx = px & 31;
      size_t idx = ((size_t)b*LL + l0 + yy)*NN + n0 + xx;
      cobf[idx] = bf16b(cacc[tt][0] + vbsum + a0[idx]);
    }
  }
}

// ---------------- K15: GEMM2, A from bf16 co, B pre-packed + de-normalize from muv/sdv ----------------
__global__ __launch_bounds__(256) void k_gemm2(const unsigned short* __restrict__ cobf,
    const unsigned* __restrict__ ldwbf, const float* __restrict__ ldb,
    const float* __restrict__ muv, const float* __restrict__ sdv,
    float* __restrict__ out){
  __shared__ unsigned Asu[64*20];
  __shared__ unsigned Bsu[32*20];
  int tid = threadIdx.x;
  int row0 = blockIdx.x*64, p0 = blockIdx.y*32;
  int b = row0 >> 7, n0 = row0 & 127;
  int lane = tid & 63, wv = tid >> 6;
  frag_cd acc[2] = {};
  int an = tid & 63, akq = (tid >> 6)*8;
  int btk = tid & 15, blc = tid >> 4;
  unsigned ra[4], rbq[2];
  #pragma unroll
  for(int u=0;u<4;u++){
    unsigned lo = cobf[((size_t)b*LL + akq + 2*u)*NN + n0 + an];
    unsigned hi = cobf[((size_t)b*LL + akq + 2*u + 1)*NN + n0 + an];
    ra[u] = lo | (hi << 16);
  }
  #pragma unroll
  for(int u=0;u<2;u++)
    rbq[u] = ldwbf[(size_t)(p0 + blc + 16*u)*384 + btk];
  int fr = wv*16 + (lane & 15);
  int fq = (lane >> 4)*4;
  for(int k0=0;k0<LL;k0+=32){
    *(uint4*)&Asu[an*20 + (akq>>1)] = make_uint4(ra[0], ra[1], ra[2], ra[3]);
    #pragma unroll
    for(int p=0;p<2;p++) Bsu[(blc + 16*p)*20 + btk] = rbq[p];
    __syncthreads();
    if(k0 + 32 < LL){
      #pragma unroll
      for(int u=0;u<4;u++){
        unsigned lo = cobf[((size_t)b*LL + k0 + 32 + akq + 2*u)*NN + n0 + an];
        unsigned hi = cobf[((size_t)b*LL + k0 + 32 + akq + 2*u + 1)*NN + n0 + an];
        ra[u] = lo | (hi << 16);
      }
      #pragma unroll
      for(int u=0;u<2;u++)
        rbq[u] = ldwbf[(size_t)(p0 + blc + 16*u)*384 + ((k0 + 32) >> 1) + btk];
    }
    frag_ab af = *(const frag_ab*)&Asu[fr*20 + fq];
    #pragma unroll
    for(int nt=0;nt<2;nt++){
      frag_ab bf = *(const frag_ab*)&Bsu[(nt*16 + (lane & 15))*20 + fq];
      acc[nt] = __builtin_amdgcn_mfma_f32_16x16x32_bf16(af, bf, acc[nt], 0, 0, 0);
    }
    __syncthreads();
  }
  int col = lane & 15, quad = lane >> 4;
  float mu_r[4], sd_r[4];
  #pragma unroll
  for(int r=0;r<4;r++){
    int row = row0 + wv*16 + quad*4 + r;
    mu_r[r] = muv[row];
    sd_r[r] = sdv[row];
  }
  #pragma unroll
  for(int nt=0;nt<2;nt++){
    int p = p0 + nt*16 + col;
    float lb = ldb[p];
    float4 st;
    st.x = (acc[nt][0] + lb)*sd_r[0] + mu_r[0];
    st.y = (acc[nt][1] + lb)*sd_r[1] + mu_r[1];
    st.z = (acc[nt][2] + lb)*sd_r[2] + mu_r[2];
    st.w = (acc[nt][3] + lb)*sd_r[3] + mu_r[3];
    *(float4*)&out[((size_t)b*PREDN + p)*NN + n0 + wv*16 + quad*4] = st;
  }
}

extern "C" void kernel_launch(void* const* d_in, const int* in_sizes, int n_in,
                              void* d_out, int out_size, void* d_ws, size_t ws_size,
                              hipStream_t stream){
  (void)in_sizes; (void)n_in; (void)out_size; (void)ws_size;
  const float* batch_x = (const float*)d_in[0];
  const float* le_w  = (const float*)d_in[4];
  const float* le_b  = (const float*)d_in[5];
  const float* c1_w  = (const float*)d_in[6];
  const float* c1_b  = (const float*)d_in[7];
  const float* bn1_g = (const float*)d_in[8];
  const float* bn1_b = (const float*)d_in[9];
  const float* c2_w  = (const float*)d_in[10];
  const float* c2_b  = (const float*)d_in[11];
  const float* bn2_g = (const float*)d_in[12];
  const float* bn2_b = (const float*)d_in[13];
  const float* i1_w0 = (const float*)d_in[14];
  const float* i1_b0 = (const float*)d_in[15];
  const float* i1_w1 = (const float*)d_in[16];
  const float* i1_b1 = (const float*)d_in[17];
  const float* i2_w0 = (const float*)d_in[18];
  const float* i2_b0 = (const float*)d_in[19];
  const float* i2_w1 = (const float*)d_in[20];
  const float* i2_b1 = (const float*)d_in[21];
  const float* ld_w  = (const float*)d_in[22];
  const float* ld_b  = (const float*)d_in[23];
  float* out = (float*)d_out;

  float* ws   = (float*)d_ws;
  float* muv  = ws;                          // 2048
  float* sdv  = muv + 2048;                  // 2048
  float* wT1  = sdv + 2048;                  // 196,608
  float* wT2  = wT1 + 196608;                // 65,536
  float* x    = wT2 + 65536;                 // 1,572,864
  float* a0   = x + (size_t)BB*NN*LL;        // 1,572,864
  float* t1   = a0 + (size_t)BB*LL*NN;       // 131,072
  float* t1t  = t1 + (size_t)BB*NN*64;       // 131,072
  float* Msp1 = t1t + (size_t)BB*64*NN;      // 131,072
  float* t2   = Msp1 + (size_t)BB*64*NN;     // 32,768
  float* t2t  = t2 + (size_t)BB*NN*16;       // 32,768
  float* Msp2 = t2t + (size_t)BB*16*NN;      // 32,768
  float* fB1  = Msp2 + (size_t)BB*16*NN;
  unsigned short* xbf = (unsigned short*)fB1;       // 1,048,576 u16 = 524,288 floats
  float* fB2  = fB1 + 524288;
  unsigned* lewbf = (unsigned*)fB2;                 // 196,608 uints
  float* fB3  = fB2 + 196608;
  unsigned* ldwbf = (unsigned*)fB3;                 // 98,304 uints
  float* fB4  = fB3 + 98304;
  uint4* bwpk = (uint4*)fB4;                        // 128 uint4
  float* fB5  = fB4 + 512;
  uint4* awpk = (uint4*)fB5;                        // 36 uint4
  float* fB6  = fB5 + 144;
  float* bsum = fB6;                                // 32
  float* fB7  = fB6 + 32;
  unsigned short* cobf = (unsigned short*)fB7;      // 1,572,864 u16 = 786,432 floats

  k_pre<<<577, 128, 0, stream>>>(batch_x, i2_w0, i2_w1, c1_w, c2_w,
                                 i1_w0, i1_w1, i1_b0, i1_b1, le_w, ld_w,
                                 muv, sdv, xbf, wT1, wT2, bwpk, awpk, bsum, lewbf, ldwbf);
  k_gemm1<<<dim3(32,12), 256, 0, stream>>>(xbf, lewbf, le_b, x, a0);
  k_conv1<<<dim3(16,BB), 512, 0, stream>>>(x, wT1, c1_b, t1);
  k_bs64<<<BB, 256, 0, stream>>>(t1, bn1_g, bn1_b, wT2, c2_b, t1t, Msp1, t2);
  k_bs16<<<BB, 256, 0, stream>>>(t2, bn2_g, bn2_b, t2t, Msp2);
  k_h12<<<dim3(96,4,BB), 256, 0, stream>>>(a0, t1t, Msp1, t2t, Msp2,
                                           bwpk, awpk, bsum, i2_b0, i2_b1, cobf);
  k_gemm2<<<dim3(32,8), 256, 0, stream>>>(cobf, ldwbf, ld_b, muv, sdv, out);
}

// Round 8
// 255.595 us; speedup vs baseline: 1.3134x; 1.3134x over previous
//
#include <hip/hip_runtime.h>
#include <hip/hip_bf16.h>
#include <math.h>

#define BB 16
#define TT 512
#define NN 128
#define PREDN 256
#define DMC 32
#define LL 768
constexpr float EPSF = 1e-5f;
using bf16 = __hip_bfloat16;
using frag_ab = __attribute__((ext_vector_type(8))) short;   // 8 bf16
using frag_cd = __attribute__((ext_vector_type(4))) float;   // 4 f32

__device__ __forceinline__ unsigned pbf2(float a, float b){
  union { bf16 h; unsigned short u; } x, y;
  x.h = __float2bfloat16(a); y.h = __float2bfloat16(b);
  return (unsigned)x.u | ((unsigned)y.u << 16);
}

__device__ __forceinline__ unsigned short bf16b(float v){
  union { bf16 h; unsigned short u; } x;
  x.h = __float2bfloat16(v);
  return x.u;
}

__device__ __forceinline__ float gelu_fast(float s){
  float s2v = s*s;
  float e = exp2f(s*fmaf(s2v, 0.10294396f, 2.30211806f));
  return s*e*__builtin_amdgcn_rcpf(e + 1.f);
}

// ---------------- K_pre: norm front-end (stats+mu/sd+xbf) + weight transposes + bf16 packing ----------------
// Roles by blockIdx.x:
//   [0,128)    norm: block=(b, 16-col group): stats + muv/sdv + xbf
//   [128,256)  wT1 transpose
//   [256,384)  wT2 transpose
//   384        bwpk/awpk/bsum packing
//   [385,513)  lewbf packing
//   [513,577)  ldwbf packing
__global__ void k_pre(const float* __restrict__ bx, const float* __restrict__ v0,
                      const float* __restrict__ v1, const float* __restrict__ w1c,
                      const float* __restrict__ w2c, const float* __restrict__ w0s1,
                      const float* __restrict__ w1s1, const float* __restrict__ b0s1,
                      const float* __restrict__ b1s1, const float* __restrict__ lew,
                      const float* __restrict__ ldw,
                      float* __restrict__ muv, float* __restrict__ sdv,
                      unsigned short* __restrict__ xbf,
                      float* __restrict__ wT1, float* __restrict__ wT2,
                      uint4* __restrict__ bwpk, uint4* __restrict__ awpk,
                      float* __restrict__ bsum, unsigned* __restrict__ lewbf,
                      unsigned* __restrict__ ldwbf){
  __shared__ float sr[8][16], s2r[8][16], bmu[16], brs[16];
  int blk = blockIdx.x;
  int tid = threadIdx.x;
  if(blk < 128){
    int b = blk >> 3, n0 = (blk & 7)*16;
    int c = tid & 15, ch = tid >> 4;        // 8 chunks of 64 t
    const float* p = bx + ((size_t)b*TT + ch*64)*NN + n0 + c;
    float s = 0.f, s2 = 0.f;
    for(int t=0;t<64;t++){ float v = p[(size_t)t*NN]; s += v; s2 += v*v; }
    sr[ch][c] = s; s2r[ch][c] = s2;
    __syncthreads();
    if(tid < 16){
      float ss = 0.f, ss2 = 0.f;
      #pragma unroll
      for(int k2=0;k2<8;k2++){ ss += sr[k2][tid]; ss2 += s2r[k2][tid]; }
      float m = ss*(1.f/512.f);
      float var = fmaxf(ss2*(1.f/512.f) - m*m, 0.f);
      float sd = sqrtf(var + EPSF);
      muv[b*NN + n0 + tid] = m;
      sdv[b*NN + n0 + tid] = sd;
      bmu[tid] = m; brs[tid] = 1.f/sd;
    }
    __syncthreads();
    for(int i=tid; i<512*8; i+=128){
      int t = i >> 3, cp = i & 7;
      const float* q = bx + ((size_t)b*TT + t)*NN + n0 + cp*2;
      float v0x = (q[0] - bmu[cp*2])*brs[cp*2];
      float v1x = (q[1] - bmu[cp*2+1])*brs[cp*2+1];
      *(unsigned*)&xbf[((size_t)b*TT + t)*NN + n0 + cp*2] = pbf2(v0x, v1x);
    }
  } else if(blk < 256){
    int o = blk - 128;
    for(int k=tid; k<1536; k+=128)
      wT1[(size_t)k*NN + o] = w1c[(size_t)o*1536 + k];
  } else if(blk < 384){
    int o = blk - 256;
    for(int k=tid; k<512; k+=128)
      wT2[(size_t)k*NN + o] = w2c[(size_t)o*512 + k];
  } else if(blk == 384){
    int i = tid;
    {
      int c = i >> 2, kq = i & 3;
      float w8[8];
      #pragma unroll
      for(int j=0;j<8;j++){
        int k = kq*8+j; float w = 0.f;
        if(k < 27){
          int ci = k/9, r9 = k - ci*9, dy = r9/3, dx = r9 - dy*3;
          w = 0.5f*w1s1[((c*3+ci)*3+dy)*3+dx];
          if(dy==1 && dx==1) w += 0.5f*w0s1[c*3+ci];
        }
        w8[j] = w;
      }
      bwpk[i] = make_uint4(pbf2(w8[0],w8[1]), pbf2(w8[2],w8[3]),
                           pbf2(w8[4],w8[5]), pbf2(w8[6],w8[7]));
    }
    if(i < 36){
      int tap = i >> 2, qq = i & 3, c8 = qq*8;
      float w8[8];
      #pragma unroll
      for(int j=0;j<8;j++){
        int c = c8 + j;
        w8[j] = 0.5f*v1[c*9 + tap] + ((tap==4) ? 0.5f*v0[c] : 0.f);
      }
      awpk[i] = make_uint4(pbf2(w8[0],w8[1]), pbf2(w8[2],w8[3]),
                           pbf2(w8[4],w8[5]), pbf2(w8[6],w8[7]));
    }
    if(i < 32) bsum[i] = 0.5f*(b0s1[i] + b1s1[i]);
  } else if(blk < 513){
    int o = blk - 385;              // rows l = o*6..o*6+5
    for(int i=tid; i<1536; i+=128){
      int l = o*6 + i/256, tp = i%256;
      lewbf[(size_t)l*256 + tp] = pbf2(lew[(size_t)l*TT + 2*tp], lew[(size_t)l*TT + 2*tp + 1]);
    }
  } else {
    int o = blk - 513;              // rows p = o*4..o*4+3
    for(int i=tid; i<1536; i+=128){
      int p = o*4 + i/384, tp = i%384;
      ldwbf[(size_t)p*384 + tp] = pbf2(ldw[(size_t)p*LL + 2*tp], ldw[(size_t)p*LL + 2*tp + 1]);
    }
  }
}

// ---------------- K1: GEMM1 via bf16 MFMA, A/B from pre-packed bf16 ----------------
__global__ __launch_bounds__(256) void k_gemm1(const unsigned short* __restrict__ xbf,
    const unsigned* __restrict__ lewbf, const float* __restrict__ leb,
    float* __restrict__ x, float* __restrict__ a0){
  __shared__ unsigned Asu[64*20];
  __shared__ unsigned Bsu[64*20];
  int tid = threadIdx.x;
  int row0 = blockIdx.x*64, l0 = blockIdx.y*64;
  int b = row0 >> 7, n0 = row0 & 127;
  int lane = tid & 63, wv = tid >> 6;
  frag_cd acc[4] = {};
  int an = tid & 63, akq = (tid >> 6)*8;
  int btk = tid & 15, blc = tid >> 4;
  unsigned ra[4], rbq[4];
  #pragma unroll
  for(int u=0;u<4;u++){
    unsigned lo = xbf[((size_t)b*TT + akq + 2*u)*NN + n0 + an];
    unsigned hi = xbf[((size_t)b*TT + akq + 2*u + 1)*NN + n0 + an];
    ra[u] = lo | (hi << 16);
    rbq[u] = lewbf[(size_t)(l0 + blc + 16*u)*256 + btk];
  }
  int fr = wv*16 + (lane & 15);
  int fq = (lane >> 4)*4;
  for(int k0=0;k0<TT;k0+=32){
    *(uint4*)&Asu[an*20 + (akq>>1)] = make_uint4(ra[0], ra[1], ra[2], ra[3]);
    #pragma unroll
    for(int p=0;p<4;p++) Bsu[(blc + 16*p)*20 + btk] = rbq[p];
    __syncthreads();
    if(k0 + 32 < TT){
      #pragma unroll
      for(int u=0;u<4;u++){
        unsigned lo = xbf[((size_t)b*TT + k0 + 32 + akq + 2*u)*NN + n0 + an];
        unsigned hi = xbf[((size_t)b*TT + k0 + 32 + akq + 2*u + 1)*NN + n0 + an];
        ra[u] = lo | (hi << 16);
        rbq[u] = lewbf[(size_t)(l0 + blc + 16*u)*256 + ((k0 + 32) >> 1) + btk];
      }
    }
    frag_ab af = *(const frag_ab*)&Asu[fr*20 + fq];
    #pragma unroll
    for(int nt=0;nt<4;nt++){
      frag_ab bf = *(const frag_ab*)&Bsu[(nt*16 + (lane & 15))*20 + fq];
      acc[nt] = __builtin_amdgcn_mfma_f32_16x16x32_bf16(af, bf, acc[nt], 0, 0, 0);
    }
    __syncthreads();
  }
  int col = lane & 15, quad = lane >> 4;
  #pragma unroll
  for(int nt=0;nt<4;nt++){
    int l = l0 + nt*16 + col;
    float lb = leb[l];
    #pragma unroll
    for(int r=0;r<4;r++){
      int m = wv*16 + quad*4 + r;
      x[(size_t)(row0 + m)*LL + l] = acc[nt][r] + lb;
    }
    float4 st;
    st.x = acc[nt][0] + lb;
    st.y = acc[nt][1] + lb;
    st.z = acc[nt][2] + lb;
    st.w = acc[nt][3] + lb;
    *(float4*)&a0[((size_t)b*LL + l)*NN + n0 + wv*16 + quad*4] = st;
  }
}

// ---------------- K3: conv1 (coalesced wT, 4 j per block) ----------------
__global__ __launch_bounds__(512) void k_conv1(const float* __restrict__ x, const float* __restrict__ wT,
                                               const float* __restrict__ bias, float* __restrict__ t1){
  __shared__ alignas(16) float xs[NN*48];
  int jt = blockIdx.x, b = blockIdx.y;
  int tid = threadIdx.x;
  int o = tid & 127, jj = tid >> 7;
  for(int i=tid;i<NN*48;i+=512){
    int ci = i/48, kk = i%48;
    xs[i] = x[((size_t)b*NN + ci)*LL + jt*48 + kk];
  }
  __syncthreads();
  float a0 = 0.f, a1 = 0.f, a2 = 0.f, a3 = 0.f;
  for(int ci=0;ci<NN;ci++){
    const float* xc = xs + ci*48 + jj*12;
    const float* wc = wT + (size_t)(ci*12)*NN + o;
    #pragma unroll
    for(int kk=0;kk<12;kk+=4){
      a0 = fmaf(xc[kk+0], wc[(size_t)(kk+0)*NN], a0);
      a1 = fmaf(xc[kk+1], wc[(size_t)(kk+1)*NN], a1);
      a2 = fmaf(xc[kk+2], wc[(size_t)(kk+2)*NN], a2);
      a3 = fmaf(xc[kk+3], wc[(size_t)(kk+3)*NN], a3);
    }
  }
  int j = jt*4 + jj;
  t1[((size_t)b*NN + o)*64 + j] = (a0 + a1) + (a2 + a3) + bias[o];
}

// ---------------- K4: BN stats per channel ----------------
__global__ void k_bnstats(const float* __restrict__ t, const float* __restrict__ g, const float* __restrict__ bb,
                          int Bcnt, int Jcnt, float* __restrict__ scale, float* __restrict__ shift){
  int o = blockIdx.x;
  int tot = Bcnt*Jcnt;
  float s = 0.f, s2 = 0.f;
  for(int i=threadIdx.x; i<tot; i+=blockDim.x){
    int b = i / Jcnt, j = i % Jcnt;
    float v = t[((size_t)b*NN + o)*Jcnt + j];
    s += v; s2 += v*v;
  }
  __shared__ float rs[256], rs2[256];
  rs[threadIdx.x] = s; rs2[threadIdx.x] = s2;
  __syncthreads();
  for(int st=128; st>0; st>>=1){
    if(threadIdx.x < st){ rs[threadIdx.x] += rs[threadIdx.x+st]; rs2[threadIdx.x] += rs2[threadIdx.x+st]; }
    __syncthreads();
  }
  if(threadIdx.x == 0){
    float mu = rs[0]/tot;
    float var = fmaxf(rs2[0]/tot - mu*mu, 0.f);
    float sc = g[o] * rsqrtf(var + EPSF);
    scale[o] = sc; shift[o] = bb[o] - mu*sc;
  }
}

// ---------------- K_bnspl: fused BN apply + ELU + transpose + spline Thomas solve ----------------
template<int LK>
__global__ __launch_bounds__(256) void k_bnspl(const float* __restrict__ t, const float* __restrict__ scale,
    const float* __restrict__ shift, float* __restrict__ tt, float* __restrict__ M){
  constexpr int m = LK-2;
  __shared__ float yt[LK][NN+1];
  __shared__ float cp[m];
  __shared__ float dp[m][NN];
  int b = blockIdx.x, tid = threadIdx.x;
  // phase 1: BN+ELU, t[b][o][LK] -> yt[j][o] (coalesced global reads)
  for(int i=tid; i<LK*NN; i+=256){
    int o = i / LK, j = i - o*LK;
    float v = t[((size_t)b*NN + o)*LK + j]*scale[o] + shift[o];
    v = v > 0.f ? v : (expf(v) - 1.f);
    yt[j][o] = v;
  }
  if(tid == 0){
    float cv = 0.25f; cp[0] = cv;
    for(int i=1;i<m;i++){ cv = 1.f/(4.f - cv); cp[i] = cv; }
  }
  __syncthreads();
  // phase 1b: coalesced tt writeback [b][j][o]
  for(int i=tid; i<LK*NN; i+=256){
    int j = i >> 7, o = i & 127;
    tt[((size_t)b*LK + j)*NN + o] = yt[j][o];
  }
  // phase 2: Thomas solve per channel c (threads 0..127)
  if(tid < NN){
    int c = tid;
    const float Kc = 6.f*(LK-1)*(LK-1);
    float y0 = yt[0][c], y1 = yt[1][c];
    float dprev = 0.f;
    for(int i=0;i<m;i++){
      float y2 = yt[i+2][c];
      float r = (y2 - 2.f*y1 + y0)*Kc;
      float d = (i == 0) ? r*0.25f : (r - dprev)*cp[i];
      dp[i][c] = d; dprev = d;
      y0 = y1; y1 = y2;
    }
    float* Mb = M + (size_t)b*LK*NN + c;
    float xv = dp[m-1][c];
    Mb[(size_t)m*NN] = xv;
    for(int i=m-2;i>=0;i--){
      xv = dp[i][c] - cp[i]*xv;
      Mb[(size_t)(i+1)*NN] = xv;
    }
    Mb[0] = 0.f;
    Mb[(size_t)(LK-1)*NN] = 0.f;
  }
}

// ---------------- K8: conv2 (coalesced wT, 4 j per block) ----------------
__global__ __launch_bounds__(512) void k_conv2(const float* __restrict__ tt, const float* __restrict__ wT,
                                               const float* __restrict__ bias, float* __restrict__ t2){
  __shared__ alignas(16) float ts[16*NN];
  int jt = blockIdx.x, b = blockIdx.y;
  int tid = threadIdx.x;
  int o = tid & 127, jj = tid >> 7;
  for(int i=tid;i<16*NN;i+=512)
    ts[i] = tt[((size_t)b*64 + jt*16)*NN + i];
  __syncthreads();
  float a0 = 0.f, a1 = 0.f, a2 = 0.f, a3 = 0.f;
  for(int ci=0;ci<NN;ci++){
    const float* wc = wT + (size_t)(ci*4)*NN + o;
    const float* tc2 = ts + (jj*4)*NN + ci;
    a0 = fmaf(tc2[0*NN], wc[0*NN], a0);
    a1 = fmaf(tc2[1*NN], wc[1*NN], a1);
    a2 = fmaf(tc2[2*NN], wc[2*NN], a2);
    a3 = fmaf(tc2[3*NN], wc[3*NN], a3);
  }
  int j = jt*4 + jj;
  t2[((size_t)b*NN + o)*16 + j] = (a0 + a1) + (a2 + a3) + bias[o];
}

// ---------------- spline pair evaluation (compile-time LK; shared coefficients for 2 adjacent channels) ----------------
template<int LK>
__device__ __forceinline__ void spline_pair(const float* __restrict__ y, const float* __restrict__ M,
    int l, int b, int c0, bool ok0, bool ok1, float& v0, float& v1){
  const float hh = 1.f/(LK-1);
  float q = (float)l * (1.f/(LL-1));
  int idx = (int)floorf(q*(LK-1));
  if(idx > LK-2) idx = LK-2;
  float s = q - idx*hh;
  float u = hh - s;
  const float hh6 = hh*hh/6.f;
  const float i6h = 1.f/(6.f*hh);
  const float ih = 1.f/hh;
  float cu = u*u*u, cs = s*s*s;
  float uh = u*ih, sh = s*ih;
  const float* yb = y + ((size_t)b*LK + idx)*NN + c0;
  const float* Mb = M + ((size_t)b*LK + idx)*NN + c0;
  v0 = 0.f; v1 = 0.f;
  if(ok0){
    float yi = yb[0], yi1 = yb[NN], M0 = Mb[0], M1 = Mb[NN];
    v0 = (M0*cu + M1*cs)*i6h + (yi - M0*hh6)*uh + (yi1 - M1*hh6)*sh;
  }
  if(ok1){
    float yi = yb[1], yi1 = yb[NN+1], M0 = Mb[1], M1 = Mb[NN+1];
    v1 = (M0*cu + M1*cs)*i6h + (yi - M0*hh6)*uh + (yi1 - M1*hh6)*sh;
  }
}

// ---------------- K_h12: fully-MFMA fused stage-1 conv + GELU + stage-2 conv + residual ----------------
#define PBQ 1416
__global__ __launch_bounds__(256, 5) void k_h12(const float* __restrict__ a0,
    const float* __restrict__ y64, const float* __restrict__ M64,
    const float* __restrict__ y16, const float* __restrict__ M16,
    const uint4* __restrict__ bwpk, const uint4* __restrict__ awpk,
    const float* __restrict__ bsum, const float* __restrict__ vb0,
    const float* __restrict__ vb1, unsigned short* __restrict__ cobf){
  __shared__ alignas(16) unsigned short AsBf[3*12*36];   // bf16 a-tile [ch][yy][xx]
  __shared__ alignas(16) unsigned Au[4*PBQ];             // planar patch/h1 buffer
  int tid = threadIdx.x;
  int l0 = blockIdx.x*8, n0 = blockIdx.y*32, b = blockIdx.z;
  int lane = tid & 63, wv = tid >> 6;
  int colB = lane & 15, qg = lane >> 4;

  // ---- Phase A: stage a-tile as bf16 pairs (648 uint slots) ----
  for(int i=tid; i<648; i+=256){
    int ch = i/216, rem = i%216, yy = rem/18, xxp = rem%18;
    int xx = xxp*2;
    int gl = l0 + yy - 2, gn0 = n0 + xx - 2;
    bool okl = (gl >= 0 && gl < LL);
    bool ok0 = okl && ((unsigned)gn0 < (unsigned)NN);
    bool ok1 = okl && ((unsigned)(gn0+1) < (unsigned)NN);
    float v0 = 0.f, v1 = 0.f;
    if(ch == 0){
      if(ok0) v0 = a0[((size_t)b*LL + gl)*NN + gn0];
      if(ok1) v1 = a0[((size_t)b*LL + gl)*NN + gn0 + 1];
    } else if(okl){
      if(ch == 1) spline_pair<64>(y64, M64, gl, b, gn0, ok0, ok1, v0, v1);
      else        spline_pair<16>(y16, M16, gl, b, gn0, ok0, ok1, v0, v1);
    }
    *(unsigned*)&AsBf[i*2] = pbf2(v0, v1);
  }

  // ---- pre-packed stage-1 weight fragments + biases ----
  union U4 { uint4 q; frag_ab f; };
  U4 bw0, bw1;
  bw0.q = bwpk[colB*4 + qg];
  bw1.q = bwpk[(colB + 16)*4 + qg];
  float brA[4], brB[4];
  #pragma unroll
  for(int r=0;r<4;r++){ brA[r] = bsum[qg*4 + r]; brB[r] = bsum[16 + qg*4 + r]; }
  __syncthreads();

  // ---- Phase B1: build patches, 1 thread per 2 adjacent px (aligned u32 pair reads) ----
  {
    const unsigned* Uv = (const unsigned*)AsBf;   // u32 view: [3][12][18]
    if(tid < 176){
      if(tid < 170){
        int yy = tid/17, xp = tid - yy*17;        // px pair (yy, 2xp), (yy, 2xp+1)
        unsigned g[3][3][2];
        #pragma unroll
        for(int ci=0;ci<3;ci++)
          #pragma unroll
          for(int dy=0;dy<3;dy++){
            int base = (ci*12 + yy + dy)*18 + xp;
            g[ci][dy][0] = Uv[base];
            g[ci][dy][1] = Uv[base+1];
          }
        int px0 = yy*34 + 2*xp;
        uint4 pq;
        pq.x = g[0][0][0];
        pq.y = (g[0][0][1]&0xffffu) | (g[0][1][0]<<16);
        pq.z = (g[0][1][0]>>16) | (g[0][1][1]<<16);
        pq.w = g[0][2][0];
        *(uint4*)&Au[0*PBQ + px0*4] = pq;
        pq.x = (g[0][2][1]&0xffffu) | (g[1][0][0]<<16);
        pq.y = (g[1][0][0]>>16) | (g[1][0][1]<<16);
        pq.z = g[1][1][0];
        pq.w = (g[1][1][1]&0xffffu) | (g[1][2][0]<<16);
        *(uint4*)&Au[1*PBQ + px0*4] = pq;
        pq.x = (g[1][2][0]>>16) | (g[1][2][1]<<16);
        pq.y = g[2][0][0];
        pq.z = (g[2][0][1]&0xffffu) | (g[2][1][0]<<16);
        pq.w = (g[2][1][0]>>16) | (g[2][1][1]<<16);
        *(uint4*)&Au[2*PBQ + px0*4] = pq;
        pq.x = g[2][2][0];
        pq.y = g[2][2][1]&0xffffu;
        pq.z = 0u; pq.w = 0u;
        *(uint4*)&Au[3*PBQ + px0*4] = pq;
        int px1 = px0 + 1;
        pq.x = (g[0][0][0]>>16) | (g[0][0][1]<<16);
        pq.y = (g[0][0][1]>>16) | (g[0][1][0]&0xffff0000u);
        pq.z = g[0][1][1];
        pq.w = (g[0][2][0]>>16) | (g[0][2][1]<<16);
        *(uint4*)&Au[0*PBQ + px1*4] = pq;
        pq.x = (g[0][2][1]>>16) | (g[1][0][0]&0xffff0000u);
        pq.y = g[1][0][1];
        pq.z = (g[1][1][0]>>16) | (g[1][1][1]<<16);
        pq.w = (g[1][1][1]>>16) | (g[1][2][0]&0xffff0000u);
        *(uint4*)&Au[1*PBQ + px1*4] = pq;
        pq.x = g[1][2][1];
        pq.y = (g[2][0][0]>>16) | (g[2][0][1]<<16);
        pq.z = (g[2][0][1]>>16) | (g[2][1][0]&0xffff0000u);
        pq.w = g[2][1][1];
        *(uint4*)&Au[2*PBQ + px1*4] = pq;
        pq.x = (g[2][2][0]>>16) | (g[2][2][1]<<16);
        pq.y = g[2][2][1]>>16;
        pq.z = 0u; pq.w = 0u;
        *(uint4*)&Au[3*PBQ + px1*4] = pq;
      } else {
        int px = 340 + (tid-170)*2;
        uint4 z = make_uint4(0u,0u,0u,0u);
        #pragma unroll
        for(int q=0;q<4;q++){
          *(uint4*)&Au[q*PBQ + px*4]     = z;
          *(uint4*)&Au[q*PBQ + (px+1)*4] = z;
        }
      }
    }
  }
  __syncthreads();

  // ---- Phase B2: stage-1 MFMA (A=weights, B=patches), gelu, b64 writeback ----
  unsigned short* h1h = (unsigned short*)Au;
  frag_cd zac = {0.f, 0.f, 0.f, 0.f};
  for(int t = wv; t < 22; t += 4){
    int px = t*16 + colB;
    U4 av;
    av.q = *(const uint4*)&Au[qg*PBQ + px*4];
    frag_cd d0 = __builtin_amdgcn_mfma_f32_16x16x32_bf16(bw0.f, av.f, zac, 0, 0, 0);
    frag_cd d1 = __builtin_amdgcn_mfma_f32_16x16x32_bf16(bw1.f, av.f, zac, 0, 0, 0);
    unsigned u0 = pbf2(gelu_fast(d0[0] + brA[0]), gelu_fast(d0[1] + brA[1]));
    unsigned u1 = pbf2(gelu_fast(d0[2] + brA[2]), gelu_fast(d0[3] + brA[3]));
    unsigned u2 = pbf2(gelu_fast(d1[0] + brB[0]), gelu_fast(d1[1] + brB[1]));
    unsigned u3 = pbf2(gelu_fast(d1[2] + brB[2]), gelu_fast(d1[3] + brB[3]));
    int lo = (qg >> 1)*PBQ + px*4 + (qg & 1)*2;
    *(uint2*)&Au[lo]           = make_uint2(u0, u1);
    *(uint2*)&Au[2*PBQ + lo]   = make_uint2(u2, u3);
  }
  __syncthreads();

  // ---- Phase B3: zero h1 at invalid borders ----
  if(n0 == 0){
    for(int i=tid;i<10*32;i+=256){ int yy=i>>5, ch=i&31;
      h1h[((ch>>3)*PBQ + (yy*34)*4)*2 + (ch&7)] = 0; }
  }
  if(n0 == 96){
    for(int i=tid;i<10*32;i+=256){ int yy=i>>5, ch=i&31;
      h1h[((ch>>3)*PBQ + (yy*34+33)*4)*2 + (ch&7)] = 0; }
  }
  if(l0 == 0){
    for(int i=tid;i<34*32;i+=256){ int xx=i>>5, ch=i&31;
      h1h[((ch>>3)*PBQ + xx*4)*2 + (ch&7)] = 0; }
  }
  if(l0 == 760){
    for(int i=tid;i<34*32;i+=256){ int xx=i>>5, ch=i&31;
      h1h[((ch>>3)*PBQ + (9*34+xx)*4)*2 + (ch&7)] = 0; }
  }

  // ---- pre-packed stage-2 weight fragments ----
  U4 aw[9];
  #pragma unroll
  for(int tap=0; tap<9; tap++) aw[tap].q = awpk[tap*4 + qg];
  float vbsum = vb0[0] + vb1[0];
  __syncthreads();

  // ---- Phase C: stage-2 conv via MFMA, B-frags direct from planar h1 ----
  frag_cd cacc[4] = {};
  int baseoff[4];
  #pragma unroll
  for(int tt=0; tt<4; tt++){
    int px = (wv*4 + tt)*16 + colB;
    int yy = px >> 5, xx = px & 31;
    baseoff[tt] = qg*PBQ + (yy*34 + xx)*4;
  }
  #pragma unroll
  for(int dy=0; dy<3; dy++)
    #pragma unroll
    for(int dx=0; dx<3; dx++){
      int tap = dy*3 + dx;
      int off = (dy*34 + dx)*4;
      #pragma unroll
      for(int tt=0; tt<4; tt++){
        U4 bv;
        bv.q = *(const uint4*)&Au[baseoff[tt] + off];
        cacc[tt] = __builtin_amdgcn_mfma_f32_16x16x32_bf16(aw[tap].f, bv.f, cacc[tt], 0, 0, 0);
      }
    }
  if(lane < 16){
    #pragma unroll
    for(int tt=0; tt<4; tt++){
      int px = (wv*4 + tt)*16 + lane;
      int yy = px >> 5, xx = px & 31;
      size_t idx = ((size_t)b*LL + l0 + yy)*NN + n0 + xx;
      cobf[idx] = bf16b(cacc[tt][0] + vbsum + a0[idx]);
    }
  }
}

// ---------------- K15: GEMM2, A from bf16 co, B pre-packed + de-normalize from muv/sdv ----------------
__global__ __launch_bounds__(256) void k_gemm2(const unsigned short* __restrict__ cobf,
    const unsigned* __restrict__ ldwbf, const float* __restrict__ ldb,
    const float* __restrict__ muv, const float* __restrict__ sdv,
    float* __restrict__ out){
  __shared__ unsigned Asu[64*20];
  __shared__ unsigned Bsu[32*20];
  int tid = threadIdx.x;
  int row0 = blockIdx.x*64, p0 = blockIdx.y*32;
  int b = row0 >> 7, n0 = row0 & 127;
  int lane = tid & 63, wv = tid >> 6;
  frag_cd acc[2] = {};
  int an = tid & 63, akq = (tid >> 6)*8;
  int btk = tid & 15, blc = tid >> 4;
  unsigned ra[4], rbq[2];
  #pragma unroll
  for(int u=0;u<4;u++){
    unsigned lo = cobf[((size_t)b*LL + akq + 2*u)*NN + n0 + an];
    unsigned hi = cobf[((size_t)b*LL + akq + 2*u + 1)*NN + n0 + an];
    ra[u] = lo | (hi << 16);
  }
  #pragma unroll
  for(int u=0;u<2;u++)
    rbq[u] = ldwbf[(size_t)(p0 + blc + 16*u)*384 + btk];
  int fr = wv*16 + (lane & 15);
  int fq = (lane >> 4)*4;
  for(int k0=0;k0<LL;k0+=32){
    *(uint4*)&Asu[an*20 + (akq>>1)] = make_uint4(ra[0], ra[1], ra[2], ra[3]);
    #pragma unroll
    for(int p=0;p<2;p++) Bsu[(blc + 16*p)*20 + btk] = rbq[p];
    __syncthreads();
    if(k0 + 32 < LL){
      #pragma unroll
      for(int u=0;u<4;u++){
        unsigned lo = cobf[((size_t)b*LL + k0 + 32 + akq + 2*u)*NN + n0 + an];
        unsigned hi = cobf[((size_t)b*LL + k0 + 32 + akq + 2*u + 1)*NN + n0 + an];
        ra[u] = lo | (hi << 16);
      }
      #pragma unroll
      for(int u=0;u<2;u++)
        rbq[u] = ldwbf[(size_t)(p0 + blc + 16*u)*384 + ((k0 + 32) >> 1) + btk];
    }
    frag_ab af = *(const frag_ab*)&Asu[fr*20 + fq];
    #pragma unroll
    for(int nt=0;nt<2;nt++){
      frag_ab bf = *(const frag_ab*)&Bsu[(nt*16 + (lane & 15))*20 + fq];
      acc[nt] = __builtin_amdgcn_mfma_f32_16x16x32_bf16(af, bf, acc[nt], 0, 0, 0);
    }
    __syncthreads();
  }
  int col = lane & 15, quad = lane >> 4;
  float mu_r[4], sd_r[4];
  #pragma unroll
  for(int r=0;r<4;r++){
    int row = row0 + wv*16 + quad*4 + r;
    mu_r[r] = muv[row];
    sd_r[r] = sdv[row];
  }
  #pragma unroll
  for(int nt=0;nt<2;nt++){
    int p = p0 + nt*16 + col;
    float lb = ldb[p];
    float4 st;
    st.x = (acc[nt][0] + lb)*sd_r[0] + mu_r[0];
    st.y = (acc[nt][1] + lb)*sd_r[1] + mu_r[1];
    st.z = (acc[nt][2] + lb)*sd_r[2] + mu_r[2];
    st.w = (acc[nt][3] + lb)*sd_r[3] + mu_r[3];
    *(float4*)&out[((size_t)b*PREDN + p)*NN + n0 + wv*16 + quad*4] = st;
  }
}

extern "C" void kernel_launch(void* const* d_in, const int* in_sizes, int n_in,
                              void* d_out, int out_size, void* d_ws, size_t ws_size,
                              hipStream_t stream){
  (void)in_sizes; (void)n_in; (void)out_size; (void)ws_size;
  const float* batch_x = (const float*)d_in[0];
  const float* le_w  = (const float*)d_in[4];
  const float* le_b  = (const float*)d_in[5];
  const float* c1_w  = (const float*)d_in[6];
  const float* c1_b  = (const float*)d_in[7];
  const float* bn1_g = (const float*)d_in[8];
  const float* bn1_b = (const float*)d_in[9];
  const float* c2_w  = (const float*)d_in[10];
  const float* c2_b  = (const float*)d_in[11];
  const float* bn2_g = (const float*)d_in[12];
  const float* bn2_b = (const float*)d_in[13];
  const float* i1_w0 = (const float*)d_in[14];
  const float* i1_b0 = (const float*)d_in[15];
  const float* i1_w1 = (const float*)d_in[16];
  const float* i1_b1 = (const float*)d_in[17];
  const float* i2_w0 = (const float*)d_in[18];
  const float* i2_b0 = (const float*)d_in[19];
  const float* i2_w1 = (const float*)d_in[20];
  const float* i2_b1 = (const float*)d_in[21];
  const float* ld_w  = (const float*)d_in[22];
  const float* ld_b  = (const float*)d_in[23];
  float* out = (float*)d_out;

  float* ws   = (float*)d_ws;
  float* muv  = ws;                          // 2048
  float* sdv  = muv + 2048;                  // 2048
  float* wT1  = sdv + 2048;                  // 196,608
  float* wT2  = wT1 + 196608;                // 65,536
  float* x    = wT2 + 65536;                 // 1,572,864
  float* a0   = x + (size_t)BB*NN*LL;        // 1,572,864
  float* t1   = a0 + (size_t)BB*LL*NN;       // 131,072
  float* t1t  = t1 + (size_t)BB*NN*64;       // 131,072
  float* Msp1 = t1t + (size_t)BB*64*NN;      // 131,072
  float* t2   = Msp1 + (size_t)BB*64*NN;     // 32,768
  float* t2t  = t2 + (size_t)BB*NN*16;       // 32,768
  float* Msp2 = t2t + (size_t)BB*16*NN;      // 32,768
  float* sc1  = Msp2 + (size_t)BB*16*NN;     // 128
  float* sh1  = sc1 + NN;                    // 128
  float* sc2  = sh1 + NN;                    // 128
  float* sh2  = sc2 + NN;                    // 128
  float* fB1  = sh2 + NN;
  unsigned short* xbf = (unsigned short*)fB1;       // 1,048,576 u16 = 524,288 floats
  float* fB2  = fB1 + 524288;
  unsigned* lewbf = (unsigned*)fB2;                 // 196,608 uints
  float* fB3  = fB2 + 196608;
  unsigned* ldwbf = (unsigned*)fB3;                 // 98,304 uints
  float* fB4  = fB3 + 98304;
  uint4* bwpk = (uint4*)fB4;                        // 128 uint4
  float* fB5  = fB4 + 512;
  uint4* awpk = (uint4*)fB5;                        // 36 uint4
  float* fB6  = fB5 + 144;
  float* bsum = fB6;                                // 32
  float* fB7  = fB6 + 32;
  unsigned short* cobf = (unsigned short*)fB7;      // 1,572,864 u16 = 786,432 floats

  k_pre<<<577, 128, 0, stream>>>(batch_x, i2_w0, i2_w1, c1_w, c2_w,
                                 i1_w0, i1_w1, i1_b0, i1_b1, le_w, ld_w,
                                 muv, sdv, xbf, wT1, wT2, bwpk, awpk, bsum, lewbf, ldwbf);
  k_gemm1<<<dim3(32,12), 256, 0, stream>>>(xbf, lewbf, le_b, x, a0);
  k_conv1<<<dim3(16,BB), 512, 0, stream>>>(x, wT1, c1_b, t1);
  k_bnstats<<<NN, 256, 0, stream>>>(t1, bn1_g, bn1_b, BB, 64, sc1, sh1);
  k_bnspl<64><<<BB, 256, 0, stream>>>(t1, sc1, sh1, t1t, Msp1);
  k_conv2<<<dim3(4,BB), 512, 0, stream>>>(t1t, wT2, c2_b, t2);
  k_bnstats<<<NN, 256, 0, stream>>>(t2, bn2_g, bn2_b, BB, 16, sc2, sh2);
  k_bnspl<16><<<BB, 256, 0, stream>>>(t2, sc2, sh2, t2t, Msp2);
  k_h12<<<dim3(96,4,BB), 256, 0, stream>>>(a0, t1t, Msp1, t2t, Msp2,
                                           bwpk, awpk, bsum, i2_b0, i2_b1, cobf);
  k_gemm2<<<dim3(32,8), 256, 0, stream>>>(cobf, ldwbf, ld_b, muv, sdv, out);
}